// Round 1
// baseline (491.526 us; speedup 1.0000x reference)
//
#include <hip/hip_runtime.h>

#define B_ROWS 4096
#define T_LEN  8192
#define N_TAPS 256

// ---------------------------------------------------------------------------
// Phase 1: zi[i][j] = sum_t x[i][t] * z[j][t]   (i<4096, j<256, t<8192)
// Split-K into 4 slices for grid parallelism (1024 blocks). fp32 tiled GEMM.
// ---------------------------------------------------------------------------
#define GBM 64
#define GBN 64
#define GBK 32
#define KSLICES 4
#define KSLICE_LEN (T_LEN / KSLICES)   // 2048

__global__ __launch_bounds__(256) void fir_zi_gemm(const float* __restrict__ x,
                                                   const float* __restrict__ z,
                                                   float* __restrict__ part) {
    __shared__ float xsT[GBK][GBM + 8];   // [k][i]  stride 72 floats (16B aligned)
    __shared__ float zsT[GBK][GBN + 8];   // [k][j]
    const int jt = blockIdx.x;            // 0..3
    const int it = blockIdx.y;            // 0..63
    const int ks = blockIdx.z;            // 0..3
    const int i0 = it * GBM, j0 = jt * GBN;
    const int kbase = ks * KSLICE_LEN;
    const int tid = threadIdx.x;
    const int tx = tid & 15, ty = tid >> 4;

    float acc[4][4];
    #pragma unroll
    for (int m = 0; m < 4; ++m)
        #pragma unroll
        for (int n = 0; n < 4; ++n) acc[m][n] = 0.f;

    for (int kc = 0; kc < KSLICE_LEN; kc += GBK) {
        // stage x tile (64 rows x 32 k) and z tile: 512 float4 each, 2/thread
        #pragma unroll
        for (int q = 0; q < 2; ++q) {
            const int e  = tid + q * 256;
            const int r  = e >> 3;          // 0..63
            const int c4 = e & 7;           // 0..7  (float4 column)
            const size_t gk = (size_t)(kbase + kc + c4 * 4);
            float4 v = *(const float4*)&x[(size_t)(i0 + r) * T_LEN + gk];
            xsT[c4 * 4 + 0][r] = v.x; xsT[c4 * 4 + 1][r] = v.y;
            xsT[c4 * 4 + 2][r] = v.z; xsT[c4 * 4 + 3][r] = v.w;
            float4 w = *(const float4*)&z[(size_t)(j0 + r) * T_LEN + gk];
            zsT[c4 * 4 + 0][r] = w.x; zsT[c4 * 4 + 1][r] = w.y;
            zsT[c4 * 4 + 2][r] = w.z; zsT[c4 * 4 + 3][r] = w.w;
        }
        __syncthreads();
        #pragma unroll
        for (int k = 0; k < GBK; ++k) {
            const float4 a = *(const float4*)&xsT[k][ty * 4];
            const float4 b = *(const float4*)&zsT[k][tx * 4];
            const float am[4] = {a.x, a.y, a.z, a.w};
            const float bn[4] = {b.x, b.y, b.z, b.w};
            #pragma unroll
            for (int m = 0; m < 4; ++m)
                #pragma unroll
                for (int n = 0; n < 4; ++n)
                    acc[m][n] += am[m] * bn[n];
        }
        __syncthreads();
    }
    // write partial slice: part[((ks*B + i) * 256) + j]
    #pragma unroll
    for (int m = 0; m < 4; ++m) {
        const size_t row = (size_t)ks * B_ROWS + (i0 + ty * 4 + m);
        float4 v = make_float4(acc[m][0], acc[m][1], acc[m][2], acc[m][3]);
        *(float4*)&part[row * N_TAPS + j0 + tx * 4] = v;
    }
}

// ---------------------------------------------------------------------------
// Phase 2: reduce 4 K-slices -> zi
// ---------------------------------------------------------------------------
__global__ __launch_bounds__(256) void fir_zi_reduce(const float* __restrict__ part,
                                                     float* __restrict__ zi) {
    const int idx = blockIdx.x * 256 + threadIdx.x;      // float4 index
    const int total = B_ROWS * N_TAPS / 4;               // 262144
    if (idx >= total) return;
    float4 s = ((const float4*)part)[idx];
    #pragma unroll
    for (int q = 1; q < KSLICES; ++q) {
        float4 v = ((const float4*)part)[(size_t)q * total + idx];
        s.x += v.x; s.y += v.y; s.z += v.z; s.w += v.w;
    }
    ((float4*)zi)[idx] = s;
}

// ---------------------------------------------------------------------------
// Phase 3: FIR conv. y[i,t] = sum_{k=0..255} b[k] * xe[i, t-k]
//   xe[i,s] = x[i,s] for s>=0 ; zi[i, -1-s] for s<0
// Block: 16 rows x 512 time cols. LDS window [seg-256, seg+512) per row,
// XOR-swizzled. Thread = (row, slot): 32 consecutive outputs.
// ---------------------------------------------------------------------------
#define CROWS 16
#define TSEG  512
#define CWIN  768
#define CRS   772     // LDS row stride in floats (16B-aligned row starts)

// XOR-swizzle on float index within a row: permutes bits [2:4] by bits [5:7].
// Preserves float4 contiguity (w%4==0 -> SWZ(w+e)=SWZ(w)+e for e<4).
#define SWZ(wi) ((wi) ^ ((((wi) >> 5) & 7) << 2))

__global__ __launch_bounds__(256) void fir_conv(const float* __restrict__ x,
                                                const float* __restrict__ bco,
                                                const float* __restrict__ zi,
                                                float* __restrict__ y) {
    __shared__ float xw[CROWS * CRS];
    __shared__ float bs[N_TAPS];
    const int seg = blockIdx.x * TSEG;
    const int i0  = blockIdx.y * CROWS;
    const int tid = threadIdx.x;

    if (tid < N_TAPS) bs[tid] = bco[tid];

    // stage window: 16 rows x 768 floats = 192 float4 per row
    const int NF4 = CWIN / 4;   // 192
    for (int e = tid; e < CROWS * NF4; e += 256) {
        const int r  = e / NF4;
        const int w  = (e % NF4) * 4;
        const int s  = seg - 256 + w;          // s % 4 == 0
        float4 v;
        if (s >= 0) {
            v = *(const float4*)&x[(size_t)(i0 + r) * T_LEN + s];
        } else {
            // all of s..s+3 are negative (s is a multiple of 4, s <= -4)
            float t0v = zi[(size_t)(i0 + r) * N_TAPS + (-1 - (s + 0))];
            float t1v = zi[(size_t)(i0 + r) * N_TAPS + (-1 - (s + 1))];
            float t2v = zi[(size_t)(i0 + r) * N_TAPS + (-1 - (s + 2))];
            float t3v = zi[(size_t)(i0 + r) * N_TAPS + (-1 - (s + 3))];
            v = make_float4(t0v, t1v, t2v, t3v);
        }
        *(float4*)&xw[r * CRS + SWZ(w)] = v;
    }
    __syncthreads();

    const int r    = tid >> 4;
    const int slot = tid & 15;
    const int t0   = seg + slot * 32;
    const float* xrow = &xw[r * CRS];

    float acc[32];
    #pragma unroll
    for (int j = 0; j < 32; ++j) acc[j] = 0.f;

    for (int kk = 0; kk < N_TAPS; kk += 32) {
        // xv[p] = xe[i, t0 - kk - 32 + p], p = 0..63 (p=0 unused padding)
        float xv[64];
        const int woff = slot * 32 + 224 - kk;   // window offset of xv[0]
        #pragma unroll
        for (int c = 0; c < 16; ++c) {
            float4 v = *(const float4*)&xrow[SWZ(woff + c * 4)];
            xv[c * 4 + 0] = v.x; xv[c * 4 + 1] = v.y;
            xv[c * 4 + 2] = v.z; xv[c * 4 + 3] = v.w;
        }
        #pragma unroll
        for (int kap = 0; kap < 32; ++kap) {
            const float bv = bs[kk + kap];
            #pragma unroll
            for (int j = 0; j < 32; ++j)
                acc[j] += bv * xv[32 + j - kap];
        }
    }

    #pragma unroll
    for (int c = 0; c < 8; ++c) {
        float4 v = make_float4(acc[c * 4 + 0], acc[c * 4 + 1],
                               acc[c * 4 + 2], acc[c * 4 + 3]);
        *(float4*)&y[(size_t)(i0 + r) * T_LEN + t0 + c * 4] = v;
    }
}

// ---------------------------------------------------------------------------
extern "C" void kernel_launch(void* const* d_in, const int* in_sizes, int n_in,
                              void* d_out, int out_size, void* d_ws, size_t ws_size,
                              hipStream_t stream) {
    const float* x  = (const float*)d_in[0];
    const float* b  = (const float*)d_in[1];
    const float* z  = (const float*)d_in[2];
    float* y = (float*)d_out;

    float* zi   = (float*)d_ws;                                  // 4096*256 f32 = 4 MB
    float* part = (float*)d_ws + (size_t)B_ROWS * N_TAPS;        // 4 slices = 16 MB

    dim3 ggrid(N_TAPS / GBN, B_ROWS / GBM, KSLICES);             // 4 x 64 x 4
    fir_zi_gemm<<<ggrid, 256, 0, stream>>>(x, z, part);

    fir_zi_reduce<<<(B_ROWS * N_TAPS / 4 + 255) / 256, 256, 0, stream>>>(part, zi);

    dim3 cgrid(T_LEN / TSEG, B_ROWS / CROWS);                    // 16 x 256
    fir_conv<<<cgrid, 256, 0, stream>>>(x, b, zi, y);
}

// Round 2
// 263.492 us; speedup vs baseline: 1.8654x; 1.8654x over previous
//
#include <hip/hip_runtime.h>
#include <hip/hip_bf16.h>

#define B_ROWS 4096
#define T_LEN  8192
#define N_TAPS 256

typedef __attribute__((ext_vector_type(8))) short short8;
typedef __attribute__((ext_vector_type(4))) short short4v;
typedef __attribute__((ext_vector_type(4))) float f32x4;

__device__ inline ushort f2bf(float f) {
    __hip_bfloat16 h = __float2bfloat16(f);
    union { __hip_bfloat16 h; ushort u; } c;
    c.h = h;
    return c.u;
}

// ---------------------------------------------------------------------------
// Phase 0: cast z (256 x 8192 fp32) -> zbf (bf16)
// ---------------------------------------------------------------------------
__global__ __launch_bounds__(256) void fir_cast_z(const float* __restrict__ z,
                                                  ushort* __restrict__ zbf) {
    const int idx = (blockIdx.x * 256 + threadIdx.x) * 8;
    float4 a = *(const float4*)&z[idx];
    float4 b = *(const float4*)&z[idx + 4];
    short8 o;
    o[0] = (short)f2bf(a.x); o[1] = (short)f2bf(a.y);
    o[2] = (short)f2bf(a.z); o[3] = (short)f2bf(a.w);
    o[4] = (short)f2bf(b.x); o[5] = (short)f2bf(b.y);
    o[6] = (short)f2bf(b.z); o[7] = (short)f2bf(b.w);
    *(short8*)&zbf[idx] = o;
}

// ---------------------------------------------------------------------------
// Phase 1: zi[i][j] = sum_t x[i][t] * z[j][t]  via bf16 MFMA, split-K partials.
// Tile: M=128 (2 wave-rows), N=256 (full, 4 wave-cols), BK=64. 512 threads.
// LDS tiles row-major [row][64k] bf16, row stride 128 B, XOR-swizzled
// (byte ^= (row&7)<<4) to kill the stride-128B frag-read bank conflict (T2).
// ---------------------------------------------------------------------------
#define MT 128
#define GBK 64

__global__ __launch_bounds__(512) void fir_zi_gemm(const float* __restrict__ x,
                                                   const ushort* __restrict__ zbf,
                                                   float* __restrict__ part,
                                                   int kslices) {
    __shared__ ushort As[MT * GBK];      // 16 KB
    __shared__ ushort Bs[N_TAPS * GBK];  // 32 KB
    const int i0 = blockIdx.x * MT;
    const int ks = blockIdx.y;
    const int klen = T_LEN / kslices;
    const int kbase = ks * klen;
    const int tid = threadIdx.x;
    const int wid = tid >> 6, lane = tid & 63;
    const int wm = wid >> 2, wn = wid & 3;   // wave sub-tile (64x64) position
    const int l15 = lane & 15, lg = lane >> 4;

    f32x4 acc[4][4];
    #pragma unroll
    for (int mi = 0; mi < 4; ++mi)
        #pragma unroll
        for (int ni = 0; ni < 4; ++ni) acc[mi][ni] = (f32x4){0.f, 0.f, 0.f, 0.f};

    for (int kc = 0; kc < klen; kc += GBK) {
        // stage A: 128 rows x 64 k fp32 -> bf16. 2048 float4 chunks, 4/thread.
        #pragma unroll
        for (int q = 0; q < 4; ++q) {
            const int e = tid + q * 512;
            const int r = e >> 4;             // 0..127
            const int c4 = (e & 15) * 4;      // 0..60
            float4 v = *(const float4*)&x[(size_t)(i0 + r) * T_LEN + kbase + kc + c4];
            short4v o;
            o[0] = (short)f2bf(v.x); o[1] = (short)f2bf(v.y);
            o[2] = (short)f2bf(v.z); o[3] = (short)f2bf(v.w);
            const int boff = r * 128 + ((c4 * 2) ^ ((r & 7) << 4));
            *(short4v*)((char*)As + boff) = o;
        }
        // stage B: 256 rows x 64 k bf16. 2048 16B chunks, 4/thread.
        #pragma unroll
        for (int q = 0; q < 4; ++q) {
            const int e = tid + q * 512;
            const int r = e >> 3;             // 0..255
            const int c8 = (e & 7) * 8;       // 0..56
            short8 v = *(const short8*)&zbf[(size_t)r * T_LEN + kbase + kc + c8];
            const int boff = r * 128 + ((c8 * 2) ^ ((r & 7) << 4));
            *(short8*)((char*)Bs + boff) = v;
        }
        __syncthreads();
        #pragma unroll
        for (int ksb = 0; ksb < 2; ++ksb) {
            short8 af[4], bfr[4];
            const int cb = (lg * 8 + ksb * 32) * 2;  // byte col of this lane's frag
            #pragma unroll
            for (int mi = 0; mi < 4; ++mi) {
                const int row = wm * 64 + mi * 16 + l15;
                af[mi] = *(const short8*)((const char*)As + row * 128 + (cb ^ ((row & 7) << 4)));
            }
            #pragma unroll
            for (int ni = 0; ni < 4; ++ni) {
                const int row = wn * 64 + ni * 16 + l15;
                bfr[ni] = *(const short8*)((const char*)Bs + row * 128 + (cb ^ ((row & 7) << 4)));
            }
            #pragma unroll
            for (int mi = 0; mi < 4; ++mi)
                #pragma unroll
                for (int ni = 0; ni < 4; ++ni)
                    acc[mi][ni] = __builtin_amdgcn_mfma_f32_16x16x32_bf16(
                        af[mi], bfr[ni], acc[mi][ni], 0, 0, 0);
        }
        __syncthreads();
    }

    // C/D layout (verified m89/m91): col = lane&15, row = (lane>>4)*4 + reg
    #pragma unroll
    for (int mi = 0; mi < 4; ++mi) {
        #pragma unroll
        for (int ni = 0; ni < 4; ++ni) {
            const int gn = wn * 64 + ni * 16 + l15;
            #pragma unroll
            for (int rg = 0; rg < 4; ++rg) {
                const int gm = i0 + wm * 64 + mi * 16 + lg * 4 + rg;
                part[((size_t)ks * B_ROWS + gm) * N_TAPS + gn] = acc[mi][ni][rg];
            }
        }
    }
}

// ---------------------------------------------------------------------------
// Phase 2: reduce split-K partials -> zi
// ---------------------------------------------------------------------------
__global__ __launch_bounds__(256) void fir_zi_reduce(const float* __restrict__ part,
                                                     float* __restrict__ zi,
                                                     int kslices) {
    const int idx = blockIdx.x * 256 + threadIdx.x;      // float4 index
    const int total = B_ROWS * N_TAPS / 4;               // 262144
    if (idx >= total) return;
    float4 s = ((const float4*)part)[idx];
    for (int q = 1; q < kslices; ++q) {
        float4 v = ((const float4*)part)[(size_t)q * total + idx];
        s.x += v.x; s.y += v.y; s.z += v.z; s.w += v.w;
    }
    ((float4*)zi)[idx] = s;
}

// ---------------------------------------------------------------------------
// Phase 3: FIR conv (unchanged from R1). y[i,t] = sum_k b[k] * xe[i, t-k]
// ---------------------------------------------------------------------------
#define CROWS 16
#define TSEG  512
#define CWIN  768
#define CRS   772

#define SWZ(wi) ((wi) ^ ((((wi) >> 5) & 7) << 2))

__global__ __launch_bounds__(256) void fir_conv(const float* __restrict__ x,
                                                const float* __restrict__ bco,
                                                const float* __restrict__ zi,
                                                float* __restrict__ y) {
    __shared__ float xw[CROWS * CRS];
    __shared__ float bs[N_TAPS];
    const int seg = blockIdx.x * TSEG;
    const int i0  = blockIdx.y * CROWS;
    const int tid = threadIdx.x;

    if (tid < N_TAPS) bs[tid] = bco[tid];

    const int NF4 = CWIN / 4;   // 192
    for (int e = tid; e < CROWS * NF4; e += 256) {
        const int r  = e / NF4;
        const int w  = (e % NF4) * 4;
        const int s  = seg - 256 + w;
        float4 v;
        if (s >= 0) {
            v = *(const float4*)&x[(size_t)(i0 + r) * T_LEN + s];
        } else {
            float t0v = zi[(size_t)(i0 + r) * N_TAPS + (-1 - (s + 0))];
            float t1v = zi[(size_t)(i0 + r) * N_TAPS + (-1 - (s + 1))];
            float t2v = zi[(size_t)(i0 + r) * N_TAPS + (-1 - (s + 2))];
            float t3v = zi[(size_t)(i0 + r) * N_TAPS + (-1 - (s + 3))];
            v = make_float4(t0v, t1v, t2v, t3v);
        }
        *(float4*)&xw[r * CRS + SWZ(w)] = v;
    }
    __syncthreads();

    const int r    = tid >> 4;
    const int slot = tid & 15;
    const int t0   = seg + slot * 32;
    const float* xrow = &xw[r * CRS];

    float acc[32];
    #pragma unroll
    for (int j = 0; j < 32; ++j) acc[j] = 0.f;

    for (int kk = 0; kk < N_TAPS; kk += 32) {
        float xv[64];
        const int woff = slot * 32 + 224 - kk;
        #pragma unroll
        for (int c = 0; c < 16; ++c) {
            float4 v = *(const float4*)&xrow[SWZ(woff + c * 4)];
            xv[c * 4 + 0] = v.x; xv[c * 4 + 1] = v.y;
            xv[c * 4 + 2] = v.z; xv[c * 4 + 3] = v.w;
        }
        #pragma unroll
        for (int kap = 0; kap < 32; ++kap) {
            const float bv = bs[kk + kap];
            #pragma unroll
            for (int j = 0; j < 32; ++j)
                acc[j] += bv * xv[32 + j - kap];
        }
    }

    #pragma unroll
    for (int c = 0; c < 8; ++c) {
        float4 v = make_float4(acc[c * 4 + 0], acc[c * 4 + 1],
                               acc[c * 4 + 2], acc[c * 4 + 3]);
        *(float4*)&y[(size_t)(i0 + r) * T_LEN + t0 + c * 4] = v;
    }
}

// ---------------------------------------------------------------------------
extern "C" void kernel_launch(void* const* d_in, const int* in_sizes, int n_in,
                              void* d_out, int out_size, void* d_ws, size_t ws_size,
                              hipStream_t stream) {
    const float* x  = (const float*)d_in[0];
    const float* b  = (const float*)d_in[1];
    const float* z  = (const float*)d_in[2];
    float* y = (float*)d_out;

    char* ws = (char*)d_ws;
    float*  zi   = (float*)ws;                           // 4 MB
    ushort* zbf  = (ushort*)(ws + (4u << 20));           // 4 MB
    float*  part = (float*)(ws + (8u << 20));            // kslices * 4 MB

    int kslices = 8;
    while (kslices > 1 &&
           (size_t)(8u << 20) + (size_t)kslices * (4u << 20) > ws_size)
        kslices >>= 1;

    fir_cast_z<<<N_TAPS * T_LEN / (256 * 8), 256, 0, stream>>>(z, zbf);

    dim3 ggrid(B_ROWS / MT, kslices);
    fir_zi_gemm<<<ggrid, 512, 0, stream>>>(x, zbf, part, kslices);

    fir_zi_reduce<<<B_ROWS * N_TAPS / 4 / 256, 256, 0, stream>>>(part, zi, kslices);

    dim3 cgrid(T_LEN / TSEG, B_ROWS / CROWS);
    fir_conv<<<cgrid, 256, 0, stream>>>(x, b, zi, y);
}

// Round 3
// 126.990 us; speedup vs baseline: 3.8706x; 2.0749x over previous
//
#include <hip/hip_runtime.h>
#include <hip/hip_bf16.h>

#define B_ROWS 4096
#define T_LEN  8192
#define N_TAPS 256

typedef __attribute__((ext_vector_type(8))) short short8;
typedef __attribute__((ext_vector_type(4))) short short4v;
typedef __attribute__((ext_vector_type(4))) float f32x4;

__device__ inline ushort f2bf(float f) {
    __hip_bfloat16 h = __float2bfloat16(f);
    union { __hip_bfloat16 h; ushort u; } c;
    c.h = h;
    return c.u;
}

// ---------------------------------------------------------------------------
// Phase 0a: cast z (256 x 8192 fp32) -> zbf (bf16)
// ---------------------------------------------------------------------------
__global__ __launch_bounds__(256) void fir_cast_z(const float* __restrict__ z,
                                                  ushort* __restrict__ zbf) {
    const int idx = (blockIdx.x * 256 + threadIdx.x) * 8;
    float4 a = *(const float4*)&z[idx];
    float4 b = *(const float4*)&z[idx + 4];
    short8 o;
    o[0] = (short)f2bf(a.x); o[1] = (short)f2bf(a.y);
    o[2] = (short)f2bf(a.z); o[3] = (short)f2bf(a.w);
    o[4] = (short)f2bf(b.x); o[5] = (short)f2bf(b.y);
    o[6] = (short)f2bf(b.z); o[7] = (short)f2bf(b.w);
    *(short8*)&zbf[idx] = o;
}

// ---------------------------------------------------------------------------
// Phase 0b: build Toeplitz B-fragment table for the conv.
// wtab[a][lane] : short8, a in [0,22). Fragment for v = 16a-288:
//   elem j: bi = 16a - 32 + l15 - lg*8 - j ; value = b[bi] if 0<=bi<256 else 0
// (B-frag lane layout: n = lane&15, k = (lane>>4)*8 + j — matches the
//  verified 16x16x32 bf16 operand layout.)
// ---------------------------------------------------------------------------
__global__ void fir_build_wtab(const float* __restrict__ b,
                               ushort* __restrict__ wtab) {
    const int a = blockIdx.x;        // 0..21
    const int lane = threadIdx.x;    // 0..63
    const int l15 = lane & 15, lg = lane >> 4;
    short8 o;
    #pragma unroll
    for (int j = 0; j < 8; ++j) {
        const int bi = 16 * a - 32 + l15 - lg * 8 - j;
        const float v = (bi >= 0 && bi < N_TAPS) ? b[bi] : 0.f;
        o[j] = (short)f2bf(v);
    }
    *(short8*)&wtab[(a * 64 + lane) * 8] = o;
}

// ---------------------------------------------------------------------------
// Phase 1: zi[i][j] = sum_t x[i][t] * z[j][t]  via bf16 MFMA, split-K partials.
// (unchanged from R2 — verified)
// ---------------------------------------------------------------------------
#define MT 128
#define GBK 64

__global__ __launch_bounds__(512) void fir_zi_gemm(const float* __restrict__ x,
                                                   const ushort* __restrict__ zbf,
                                                   float* __restrict__ part,
                                                   int kslices) {
    __shared__ ushort As[MT * GBK];      // 16 KB
    __shared__ ushort Bs[N_TAPS * GBK];  // 32 KB
    const int i0 = blockIdx.x * MT;
    const int ks = blockIdx.y;
    const int klen = T_LEN / kslices;
    const int kbase = ks * klen;
    const int tid = threadIdx.x;
    const int wid = tid >> 6, lane = tid & 63;
    const int wm = wid >> 2, wn = wid & 3;
    const int l15 = lane & 15, lg = lane >> 4;

    f32x4 acc[4][4];
    #pragma unroll
    for (int mi = 0; mi < 4; ++mi)
        #pragma unroll
        for (int ni = 0; ni < 4; ++ni) acc[mi][ni] = (f32x4){0.f, 0.f, 0.f, 0.f};

    for (int kc = 0; kc < klen; kc += GBK) {
        #pragma unroll
        for (int q = 0; q < 4; ++q) {
            const int e = tid + q * 512;
            const int r = e >> 4;
            const int c4 = (e & 15) * 4;
            float4 v = *(const float4*)&x[(size_t)(i0 + r) * T_LEN + kbase + kc + c4];
            short4v o;
            o[0] = (short)f2bf(v.x); o[1] = (short)f2bf(v.y);
            o[2] = (short)f2bf(v.z); o[3] = (short)f2bf(v.w);
            const int boff = r * 128 + ((c4 * 2) ^ ((r & 7) << 4));
            *(short4v*)((char*)As + boff) = o;
        }
        #pragma unroll
        for (int q = 0; q < 4; ++q) {
            const int e = tid + q * 512;
            const int r = e >> 3;
            const int c8 = (e & 7) * 8;
            short8 v = *(const short8*)&zbf[(size_t)r * T_LEN + kbase + kc + c8];
            const int boff = r * 128 + ((c8 * 2) ^ ((r & 7) << 4));
            *(short8*)((char*)Bs + boff) = v;
        }
        __syncthreads();
        #pragma unroll
        for (int ksb = 0; ksb < 2; ++ksb) {
            short8 af[4], bfr[4];
            const int cb = (lg * 8 + ksb * 32) * 2;
            #pragma unroll
            for (int mi = 0; mi < 4; ++mi) {
                const int row = wm * 64 + mi * 16 + l15;
                af[mi] = *(const short8*)((const char*)As + row * 128 + (cb ^ ((row & 7) << 4)));
            }
            #pragma unroll
            for (int ni = 0; ni < 4; ++ni) {
                const int row = wn * 64 + ni * 16 + l15;
                bfr[ni] = *(const short8*)((const char*)Bs + row * 128 + (cb ^ ((row & 7) << 4)));
            }
            #pragma unroll
            for (int mi = 0; mi < 4; ++mi)
                #pragma unroll
                for (int ni = 0; ni < 4; ++ni)
                    acc[mi][ni] = __builtin_amdgcn_mfma_f32_16x16x32_bf16(
                        af[mi], bfr[ni], acc[mi][ni], 0, 0, 0);
        }
        __syncthreads();
    }

    #pragma unroll
    for (int mi = 0; mi < 4; ++mi) {
        #pragma unroll
        for (int ni = 0; ni < 4; ++ni) {
            const int gn = wn * 64 + ni * 16 + l15;
            #pragma unroll
            for (int rg = 0; rg < 4; ++rg) {
                const int gm = i0 + wm * 64 + mi * 16 + lg * 4 + rg;
                part[((size_t)ks * B_ROWS + gm) * N_TAPS + gn] = acc[mi][ni][rg];
            }
        }
    }
}

// ---------------------------------------------------------------------------
// Phase 2: reduce split-K partials -> zi
// ---------------------------------------------------------------------------
__global__ __launch_bounds__(256) void fir_zi_reduce(const float* __restrict__ part,
                                                     float* __restrict__ zi,
                                                     int kslices) {
    const int idx = blockIdx.x * 256 + threadIdx.x;
    const int total = B_ROWS * N_TAPS / 4;
    if (idx >= total) return;
    float4 s = ((const float4*)part)[idx];
    for (int q = 1; q < kslices; ++q) {
        float4 v = ((const float4*)part)[(size_t)q * total + idx];
        s.x += v.x; s.y += v.y; s.z += v.z; s.w += v.w;
    }
    ((float4*)zi)[idx] = s;
}

// ---------------------------------------------------------------------------
// Phase 3: FIR conv via MFMA.
//   y[i, tc64+n] = sum_{q=0..319} xe[i, tc64-256+q] * Wc[q][n]
//   Wc[q][n] = b[n+256-q] if in [0,255] else 0  (banded Toeplitz)
// Block: 16 rows x 1024 outputs (16 chunks of 64). 4 waves, 4 chunks each.
// xe window [t0-256, t0+1024) staged bf16 in LDS, XOR-swizzled.
// W B-frags: 18 nonzero fragments in VGPRs, loaded from wtab.
// ---------------------------------------------------------------------------
#define VBM 16
#define VBT 1024
#define VWIN 1280
#define VSTR 2560   // LDS row stride, bytes (20 x 128B blocks -> swizzle-safe)

__global__ __launch_bounds__(256, 2) void fir_conv_mfma(
        const float* __restrict__ x,
        const ushort* __restrict__ wtab,
        const float* __restrict__ zi,
        float* __restrict__ y) {
    __shared__ ushort xe[VBM * VSTR / 2];   // 40960 B
    const int t0 = blockIdx.x * VBT;
    const int i0 = blockIdx.y * VBM;
    const int tid = threadIdx.x;
    const int lane = tid & 63, wid = tid >> 6;
    const int l15 = lane & 15, lg = lane >> 4;

    // W fragments a = 2..19  (a<2 and a>19 are structurally all-zero)
    short8 wf[18];
    #pragma unroll
    for (int a = 0; a < 18; ++a)
        wf[a] = *(const short8*)&wtab[((a + 2) * 64 + lane) * 8];

    // --- stage main region: cols [256, 1280) = x[t0 .. t0+1024) ---
    #pragma unroll
    for (int it = 0; it < 8; ++it) {
        const int e = tid + it * 256;
        const int r = e >> 7;            // 0..15
        const int c8 = e & 127;          // 8-col group
        const int g = t0 + c8 * 8;
        float4 v0 = *(const float4*)&x[(size_t)(i0 + r) * T_LEN + g];
        float4 v1 = *(const float4*)&x[(size_t)(i0 + r) * T_LEN + g + 4];
        short8 o;
        o[0] = (short)f2bf(v0.x); o[1] = (short)f2bf(v0.y);
        o[2] = (short)f2bf(v0.z); o[3] = (short)f2bf(v0.w);
        o[4] = (short)f2bf(v1.x); o[5] = (short)f2bf(v1.y);
        o[6] = (short)f2bf(v1.z); o[7] = (short)f2bf(v1.w);
        const int off = (512 + c8 * 16) ^ ((r & 7) << 4);
        *(short8*)((char*)xe + r * VSTR + off) = o;
    }
    // --- stage halo: cols [0, 256) = xe[t0-256 .. t0) ---
    #pragma unroll
    for (int it = 0; it < 2; ++it) {
        const int e = tid + it * 256;
        const int r = e >> 5;            // 0..15
        const int c8 = e & 31;
        const int g = t0 - 256 + c8 * 8;
        short8 o;
        if (g >= 0) {
            float4 v0 = *(const float4*)&x[(size_t)(i0 + r) * T_LEN + g];
            float4 v1 = *(const float4*)&x[(size_t)(i0 + r) * T_LEN + g + 4];
            o[0] = (short)f2bf(v0.x); o[1] = (short)f2bf(v0.y);
            o[2] = (short)f2bf(v0.z); o[3] = (short)f2bf(v0.w);
            o[4] = (short)f2bf(v1.x); o[5] = (short)f2bf(v1.y);
            o[6] = (short)f2bf(v1.z); o[7] = (short)f2bf(v1.w);
        } else {
            // xe[i, g+jj] = zi[i, -1-g-jj]   (g=-256,jj=0 -> zi[255]: coeff 0)
            #pragma unroll
            for (int jj = 0; jj < 8; ++jj)
                o[jj] = (short)f2bf(zi[(size_t)(i0 + r) * N_TAPS + (-1 - g - jj)]);
        }
        const int off = (c8 * 16) ^ ((r & 7) << 4);
        *(short8*)((char*)xe + r * VSTR + off) = o;
    }
    __syncthreads();

    f32x4 acc[4][4];   // [chunk][ncol]
    #pragma unroll
    for (int c4 = 0; c4 < 4; ++c4)
        #pragma unroll
        for (int n = 0; n < 4; ++n) acc[c4][n] = (f32x4){0.f, 0.f, 0.f, 0.f};

    const int chunk0 = wid * 4;
    #pragma unroll
    for (int ui = 0; ui < 10; ++ui) {
        #pragma unroll
        for (int c4 = 0; c4 < 4; ++c4) {
            const int colw = (chunk0 + c4) * 64 + ui * 32 + lg * 8;
            const int off = (colw * 2) ^ ((l15 & 7) << 4);
            short8 af = *(const short8*)((const char*)xe + l15 * VSTR + off);
            #pragma unroll
            for (int ncol = 0; ncol < 4; ++ncol) {
                const int a = ncol + 18 - 2 * ui;   // compile-time after unroll
                if (a >= 2 && a <= 19)
                    acc[c4][ncol] = __builtin_amdgcn_mfma_f32_16x16x32_bf16(
                        af, wf[a - 2], acc[c4][ncol], 0, 0, 0);
            }
        }
    }

    // D layout: n (time) = lane&15, m (row) = (lane>>4)*4 + reg
    #pragma unroll
    for (int c4 = 0; c4 < 4; ++c4) {
        #pragma unroll
        for (int ncol = 0; ncol < 4; ++ncol) {
            const size_t tcol = (size_t)t0 + (chunk0 + c4) * 64 + ncol * 16 + l15;
            #pragma unroll
            for (int rg = 0; rg < 4; ++rg) {
                y[(size_t)(i0 + lg * 4 + rg) * T_LEN + tcol] = acc[c4][ncol][rg];
            }
        }
    }
}

// ---------------------------------------------------------------------------
extern "C" void kernel_launch(void* const* d_in, const int* in_sizes, int n_in,
                              void* d_out, int out_size, void* d_ws, size_t ws_size,
                              hipStream_t stream) {
    const float* x  = (const float*)d_in[0];
    const float* b  = (const float*)d_in[1];
    const float* z  = (const float*)d_in[2];
    float* y = (float*)d_out;

    char* ws = (char*)d_ws;
    float*  zi   = (float*)ws;                            // 4 MB
    ushort* zbf  = (ushort*)(ws + (4u << 20));            // 4 MB
    ushort* wtab = (ushort*)(ws + (8u << 20));            // 22.5 KB (reserve 64K)
    float*  part = (float*)(ws + (8u << 20) + (64u << 10));

    int kslices = 8;
    while (kslices > 1 &&
           (size_t)(8u << 20) + (64u << 10) + (size_t)kslices * (4u << 20) > ws_size)
        kslices >>= 1;

    fir_build_wtab<<<22, 64, 0, stream>>>(b, wtab);
    fir_cast_z<<<N_TAPS * T_LEN / (256 * 8), 256, 0, stream>>>(z, zbf);

    dim3 ggrid(B_ROWS / MT, kslices);
    fir_zi_gemm<<<ggrid, 512, 0, stream>>>(x, zbf, part, kslices);

    fir_zi_reduce<<<B_ROWS * N_TAPS / 4 / 256, 256, 0, stream>>>(part, zi, kslices);

    dim3 cgrid(T_LEN / VBT, B_ROWS / VBM);                // 8 x 256
    fir_conv_mfma<<<cgrid, 256, 0, stream>>>(x, wtab, zi, y);
}

// Round 4
// 110.251 us; speedup vs baseline: 4.4582x; 1.1518x over previous
//
#include <hip/hip_runtime.h>
#include <hip/hip_bf16.h>

#define B_ROWS 4096
#define T_LEN  8192
#define N_TAPS 256

typedef __attribute__((ext_vector_type(8))) short short8;
typedef __attribute__((ext_vector_type(4))) short short4v;
typedef __attribute__((ext_vector_type(4))) float f32x4;

__device__ inline ushort f2bf(float f) {
    __hip_bfloat16 h = __float2bfloat16(f);
    union { __hip_bfloat16 h; ushort u; } c;
    c.h = h;
    return c.u;
}

// async global->LDS, 16 B per lane. LDS dest = wave-uniform base + lane*16.
typedef __attribute__((address_space(1))) const void g_void;
typedef __attribute__((address_space(3))) void s_void;
__device__ inline void gload16(const void* g, void* s) {
    __builtin_amdgcn_global_load_lds((g_void*)g, (s_void*)s, 16, 0, 0);
}

// ---------------------------------------------------------------------------
// Phase 0a: cast z (256 x 8192 fp32) -> zbf (bf16)
// ---------------------------------------------------------------------------
__global__ __launch_bounds__(256) void fir_cast_z(const float* __restrict__ z,
                                                  ushort* __restrict__ zbf) {
    const int idx = (blockIdx.x * 256 + threadIdx.x) * 8;
    float4 a = *(const float4*)&z[idx];
    float4 b = *(const float4*)&z[idx + 4];
    short8 o;
    o[0] = (short)f2bf(a.x); o[1] = (short)f2bf(a.y);
    o[2] = (short)f2bf(a.z); o[3] = (short)f2bf(a.w);
    o[4] = (short)f2bf(b.x); o[5] = (short)f2bf(b.y);
    o[6] = (short)f2bf(b.z); o[7] = (short)f2bf(b.w);
    *(short8*)&zbf[idx] = o;
}

// ---------------------------------------------------------------------------
// Phase 0b: Toeplitz B-fragment table (unchanged, verified R3)
// ---------------------------------------------------------------------------
__global__ void fir_build_wtab(const float* __restrict__ b,
                               ushort* __restrict__ wtab) {
    const int a = blockIdx.x;        // 0..21
    const int lane = threadIdx.x;    // 0..63
    const int l15 = lane & 15, lg = lane >> 4;
    short8 o;
    #pragma unroll
    for (int j = 0; j < 8; ++j) {
        const int bi = 16 * a - 32 + l15 - lg * 8 - j;
        const float v = (bi >= 0 && bi < N_TAPS) ? b[bi] : 0.f;
        o[j] = (short)f2bf(v);
    }
    *(short8*)&wtab[(a * 64 + lane) * 8] = o;
}

// ---------------------------------------------------------------------------
// Phase 1: zi GEMM, structurally double-buffered 2-phase pipeline.
//  - B staged by global_load_lds (linear LDS dest, PRE-SWIZZLED global src:
//    lds[row][c] <- global(row, c ^ (row&7)); read uses same XOR involution)
//  - A staged via reg (fp32->bf16 cvt): loads for tile t+1 issued BEFORE the
//    MFMA block of tile t, cvt+ds_write after (T14 async-STAGE split)
//  - one __syncthreads per k-iter (its vmcnt(0) drains the gload_lds queue)
// ---------------------------------------------------------------------------
#define MT 128
#define GBK 64
#define ASZ (MT * GBK)        // 8192 ushorts = 16 KB
#define BSZ (N_TAPS * GBK)    // 16384 ushorts = 32 KB

__global__ __launch_bounds__(512) void fir_zi_gemm(const float* __restrict__ x,
                                                   const ushort* __restrict__ zbf,
                                                   float* __restrict__ part,
                                                   int kslices) {
    __shared__ ushort As[2 * ASZ];   // 32 KB
    __shared__ ushort Bs[2 * BSZ];   // 64 KB
    const int i0 = blockIdx.x * MT;
    const int ks = blockIdx.y;
    const int klen = T_LEN / kslices;
    const int kbase = ks * klen;
    const int tid = threadIdx.x;
    const int wid = tid >> 6, lane = tid & 63;
    const int wm = wid >> 2, wn = wid & 3;
    const int l15 = lane & 15, lg = lane >> 4;

    // A staging coords: round q covers rows q*32 + (tid>>4), col chunk (tid&15)*4
    const int a_r0 = tid >> 4;          // row within 32-row group
    const int a_c4 = (tid & 15) * 4;    // fp32 col
    // B staging coords: round q covers rows q*64 + wid*8 + (lane>>3)
    const int b_rl = lane >> 3;         // row within wave's 8-row group
    const int b_c  = lane & 7;          // 16B chunk within row

    f32x4 acc[4][4];
    #pragma unroll
    for (int mi = 0; mi < 4; ++mi)
        #pragma unroll
        for (int ni = 0; ni < 4; ++ni) acc[mi][ni] = (f32x4){0.f, 0.f, 0.f, 0.f};

    const int nt = klen / GBK;

    float4 apf[4];

    // ---- helpers as lambdas (inlined) ----
    auto issueA = [&](int kc) {
        #pragma unroll
        for (int q = 0; q < 4; ++q) {
            const int r = a_r0 + q * 32;
            apf[q] = *(const float4*)&x[(size_t)(i0 + r) * T_LEN + kbase + kc + a_c4];
        }
    };
    auto issueB = [&](int kc, int buf) {
        #pragma unroll
        for (int q = 0; q < 4; ++q) {
            const int row = q * 64 + wid * 8 + b_rl;
            const int gc  = b_c ^ (row & 7);            // pre-swizzled source
            const void* g = &zbf[(size_t)row * T_LEN + kbase + kc + gc * 8];
            void* s = (char*)&Bs[buf * BSZ] + (q * 8 + wid) * 1024;  // wave-uniform
            gload16(g, s);
        }
    };
    auto writeA = [&](int buf) {
        #pragma unroll
        for (int q = 0; q < 4; ++q) {
            const int r = a_r0 + q * 32;
            short4v o;
            o[0] = (short)f2bf(apf[q].x); o[1] = (short)f2bf(apf[q].y);
            o[2] = (short)f2bf(apf[q].z); o[3] = (short)f2bf(apf[q].w);
            const int boff = r * 128 + ((a_c4 * 2) ^ ((r & 7) << 4));
            *(short4v*)((char*)&As[buf * ASZ] + boff) = o;
        }
    };

    // ---- prologue: tile 0 into buf 0 ----
    issueA(0);
    issueB(0, 0);
    writeA(0);          // compiler waits vmcnt for apf here
    __syncthreads();    // drains gload_lds(B0) + ds_writes

    int cur = 0;
    for (int t = 0; t < nt; ++t) {
        const int pf = (t + 1 < nt);
        if (pf) {
            issueA((t + 1) * GBK);
            issueB((t + 1) * GBK, cur ^ 1);
        }
        // ---- compute tile t from buf cur ----
        const char* Ab = (const char*)&As[cur * ASZ];
        const char* Bb = (const char*)&Bs[cur * BSZ];
        #pragma unroll
        for (int ksb = 0; ksb < 2; ++ksb) {
            short8 af[4], bfr[4];
            const int cb = (lg * 8 + ksb * 32) * 2;
            #pragma unroll
            for (int mi = 0; mi < 4; ++mi) {
                const int row = wm * 64 + mi * 16 + l15;
                af[mi] = *(const short8*)(Ab + row * 128 + (cb ^ ((row & 7) << 4)));
            }
            #pragma unroll
            for (int ni = 0; ni < 4; ++ni) {
                const int row = wn * 64 + ni * 16 + l15;
                bfr[ni] = *(const short8*)(Bb + row * 128 + (cb ^ ((row & 7) << 4)));
            }
            #pragma unroll
            for (int mi = 0; mi < 4; ++mi)
                #pragma unroll
                for (int ni = 0; ni < 4; ++ni)
                    acc[mi][ni] = __builtin_amdgcn_mfma_f32_16x16x32_bf16(
                        af[mi], bfr[ni], acc[mi][ni], 0, 0, 0);
        }
        if (pf) writeA(cur ^ 1);
        __syncthreads();
        cur ^= 1;
    }

    // C/D layout: col = lane&15, row = (lane>>4)*4 + reg
    #pragma unroll
    for (int mi = 0; mi < 4; ++mi) {
        #pragma unroll
        for (int ni = 0; ni < 4; ++ni) {
            const int gn = wn * 64 + ni * 16 + l15;
            #pragma unroll
            for (int rg = 0; rg < 4; ++rg) {
                const int gm = i0 + wm * 64 + mi * 16 + lg * 4 + rg;
                part[((size_t)ks * B_ROWS + gm) * N_TAPS + gn] = acc[mi][ni][rg];
            }
        }
    }
}

// ---------------------------------------------------------------------------
// Phase 2: reduce split-K partials -> zi
// ---------------------------------------------------------------------------
__global__ __launch_bounds__(256) void fir_zi_reduce(const float* __restrict__ part,
                                                     float* __restrict__ zi,
                                                     int kslices) {
    const int idx = blockIdx.x * 256 + threadIdx.x;
    const int total = B_ROWS * N_TAPS / 4;
    if (idx >= total) return;
    float4 s = ((const float4*)part)[idx];
    for (int q = 1; q < kslices; ++q) {
        float4 v = ((const float4*)part)[(size_t)q * total + idx];
        s.x += v.x; s.y += v.y; s.z += v.z; s.w += v.w;
    }
    ((float4*)zi)[idx] = s;
}

// ---------------------------------------------------------------------------
// Phase 3: FIR conv via MFMA (unchanged from R3 — verified, at y-write floor)
// ---------------------------------------------------------------------------
#define VBM 16
#define VBT 1024
#define VWIN 1280
#define VSTR 2560

__global__ __launch_bounds__(256, 2) void fir_conv_mfma(
        const float* __restrict__ x,
        const ushort* __restrict__ wtab,
        const float* __restrict__ zi,
        float* __restrict__ y) {
    __shared__ ushort xe[VBM * VSTR / 2];
    const int t0 = blockIdx.x * VBT;
    const int i0 = blockIdx.y * VBM;
    const int tid = threadIdx.x;
    const int lane = tid & 63, wid = tid >> 6;
    const int l15 = lane & 15, lg = lane >> 4;

    short8 wf[18];
    #pragma unroll
    for (int a = 0; a < 18; ++a)
        wf[a] = *(const short8*)&wtab[((a + 2) * 64 + lane) * 8];

    #pragma unroll
    for (int it = 0; it < 8; ++it) {
        const int e = tid + it * 256;
        const int r = e >> 7;
        const int c8 = e & 127;
        const int g = t0 + c8 * 8;
        float4 v0 = *(const float4*)&x[(size_t)(i0 + r) * T_LEN + g];
        float4 v1 = *(const float4*)&x[(size_t)(i0 + r) * T_LEN + g + 4];
        short8 o;
        o[0] = (short)f2bf(v0.x); o[1] = (short)f2bf(v0.y);
        o[2] = (short)f2bf(v0.z); o[3] = (short)f2bf(v0.w);
        o[4] = (short)f2bf(v1.x); o[5] = (short)f2bf(v1.y);
        o[6] = (short)f2bf(v1.z); o[7] = (short)f2bf(v1.w);
        const int off = (512 + c8 * 16) ^ ((r & 7) << 4);
        *(short8*)((char*)xe + r * VSTR + off) = o;
    }
    #pragma unroll
    for (int it = 0; it < 2; ++it) {
        const int e = tid + it * 256;
        const int r = e >> 5;
        const int c8 = e & 31;
        const int g = t0 - 256 + c8 * 8;
        short8 o;
        if (g >= 0) {
            float4 v0 = *(const float4*)&x[(size_t)(i0 + r) * T_LEN + g];
            float4 v1 = *(const float4*)&x[(size_t)(i0 + r) * T_LEN + g + 4];
            o[0] = (short)f2bf(v0.x); o[1] = (short)f2bf(v0.y);
            o[2] = (short)f2bf(v0.z); o[3] = (short)f2bf(v0.w);
            o[4] = (short)f2bf(v1.x); o[5] = (short)f2bf(v1.y);
            o[6] = (short)f2bf(v1.z); o[7] = (short)f2bf(v1.w);
        } else {
            #pragma unroll
            for (int jj = 0; jj < 8; ++jj)
                o[jj] = (short)f2bf(zi[(size_t)(i0 + r) * N_TAPS + (-1 - g - jj)]);
        }
        const int off = (c8 * 16) ^ ((r & 7) << 4);
        *(short8*)((char*)xe + r * VSTR + off) = o;
    }
    __syncthreads();

    f32x4 acc[4][4];
    #pragma unroll
    for (int c4 = 0; c4 < 4; ++c4)
        #pragma unroll
        for (int n = 0; n < 4; ++n) acc[c4][n] = (f32x4){0.f, 0.f, 0.f, 0.f};

    const int chunk0 = wid * 4;
    #pragma unroll
    for (int ui = 0; ui < 10; ++ui) {
        #pragma unroll
        for (int c4 = 0; c4 < 4; ++c4) {
            const int colw = (chunk0 + c4) * 64 + ui * 32 + lg * 8;
            const int off = (colw * 2) ^ ((l15 & 7) << 4);
            short8 af = *(const short8*)((const char*)xe + l15 * VSTR + off);
            #pragma unroll
            for (int ncol = 0; ncol < 4; ++ncol) {
                const int a = ncol + 18 - 2 * ui;
                if (a >= 2 && a <= 19)
                    acc[c4][ncol] = __builtin_amdgcn_mfma_f32_16x16x32_bf16(
                        af, wf[a - 2], acc[c4][ncol], 0, 0, 0);
            }
        }
    }

    #pragma unroll
    for (int c4 = 0; c4 < 4; ++c4) {
        #pragma unroll
        for (int ncol = 0; ncol < 4; ++ncol) {
            const size_t tcol = (size_t)t0 + (chunk0 + c4) * 64 + ncol * 16 + l15;
            #pragma unroll
            for (int rg = 0; rg < 4; ++rg) {
                y[(size_t)(i0 + lg * 4 + rg) * T_LEN + tcol] = acc[c4][ncol][rg];
            }
        }
    }
}

// ---------------------------------------------------------------------------
extern "C" void kernel_launch(void* const* d_in, const int* in_sizes, int n_in,
                              void* d_out, int out_size, void* d_ws, size_t ws_size,
                              hipStream_t stream) {
    const float* x  = (const float*)d_in[0];
    const float* b  = (const float*)d_in[1];
    const float* z  = (const float*)d_in[2];
    float* y = (float*)d_out;

    char* ws = (char*)d_ws;
    float*  zi   = (float*)ws;                            // 4 MB
    ushort* zbf  = (ushort*)(ws + (4u << 20));            // 4 MB
    ushort* wtab = (ushort*)(ws + (8u << 20));            // 22.5 KB (reserve 64K)
    float*  part = (float*)(ws + (8u << 20) + (64u << 10));

    int kslices = 8;
    while (kslices > 1 &&
           (size_t)(8u << 20) + (64u << 10) + (size_t)kslices * (4u << 20) > ws_size)
        kslices >>= 1;

    fir_build_wtab<<<22, 64, 0, stream>>>(b, wtab);
    fir_cast_z<<<N_TAPS * T_LEN / (256 * 8), 256, 0, stream>>>(z, zbf);

    dim3 ggrid(B_ROWS / MT, kslices);
    fir_zi_gemm<<<ggrid, 512, 0, stream>>>(x, zbf, part, kslices);

    fir_zi_reduce<<<B_ROWS * N_TAPS / 4 / 256, 256, 0, stream>>>(part, zi, kslices);

    dim3 cgrid(T_LEN / VBT, B_ROWS / VBM);                // 8 x 256
    fir_conv_mfma<<<cgrid, 256, 0, stream>>>(x, wtab, zi, y);
}